// Round 6
// baseline (272.051 us; speedup 1.0000x reference)
//
#include <hip/hip_runtime.h>

// DerivativeNet direction='x', two-phase:
//   K1: mask -> 3-bit/elem codes. Block-per-row, ONE float4/thread, per-wave
//       ballots + 128B LDS combine (1 barrier). Pure streaming shape.
//   K2: one thread per (b,y,w4) does BOTH channels: 1 code read, 2 u float4
//       streams, 4 L1-hit halo scalars, 2 NT stores. Copy-shaped, max MLP.
// B=16, C=2, H=1024, W=1024 fp32. Min traffic ~352 MB -> ~55 us floor.

#define WDIM 1024
typedef float v4f __attribute__((ext_vector_type(4)));
typedef unsigned long long ull;

// ---------------- Kernel 1: mask -> codes (1 B/elem) ----------------
__global__ __launch_bounds__(256) void mask_codes_kernel(
    const float* __restrict__ mask, unsigned int* __restrict__ codes)
{
    const int row  = blockIdx.x;            // b*1024 + y
    const int t    = threadIdx.x;           // float4 index in row (0..255)
    const int wv   = t >> 6;
    const int lane = t & 63;

    const float4 m = ((const float4*)(mask + (size_t)row * WDIM))[t];

    // ballots for this wave's 256-float span; bit l = mask at (64*wv + l)*4 + j
    const ull b0 = __ballot(m.x != 0.0f);
    const ull b1 = __ballot(m.y != 0.0f);
    const ull b2 = __ballot(m.z != 0.0f);
    const ull b3 = __ballot(m.w != 0.0f);

    __shared__ ull sb[4][4];
    if (lane == 0) { sb[wv][0] = b0; sb[wv][1] = b1; sb[wv][2] = b2; sb[wv][3] = b3; }
    __syncthreads();

    int carry = 0, total = 0;
    #pragma unroll
    for (int i = 0; i < 4; ++i) {
        const int s = __popcll(sb[i][0]) + __popcll(sb[i][1])
                    + __popcll(sb[i][2]) + __popcll(sb[i][3]);
        if (i < wv) carry += s;
        total += s;
    }

    const ull below = (1ull << lane) - 1ull;
    const int pre = carry + __popcll(b0 & below) + __popcll(b1 & below)
                          + __popcll(b2 & below) + __popcll(b3 & below);

    const int i0 = (int)m.x, i1 = (int)m.y, i2 = (int)m.z, i3 = (int)m.w;
    const int cs0 = pre + i0, cs1 = cs0 + i1, cs2 = cs1 + i2, cs3 = cs2 + i3;

    // halo bits across lanes/waves (zero-padded at row ends)
    const ull mlw = (b3 << 1) | (wv > 0 ? (sb[wv - 1][3] >> 63) : 0ull);
    const ull mrw = (b0 >> 1) | (wv < 3 ? (sb[wv + 1][0] << 63) : 0ull);
    const int ml = (int)((mlw >> lane) & 1ull);
    const int mr = (int)((mrw >> lane) & 1ull);

    // bits: 0 = eroded (3-box==3), 1 = (cs==1), 2 = (mask && cs==total)
    const unsigned cb0 = (unsigned)(ml + i0 + i1 == 3) | ((unsigned)(cs0 == 1) << 1)
                       | ((unsigned)(i0 && cs0 == total) << 2);
    const unsigned cb1 = (unsigned)(i0 + i1 + i2 == 3) | ((unsigned)(cs1 == 1) << 1)
                       | ((unsigned)(i1 && cs1 == total) << 2);
    const unsigned cb2 = (unsigned)(i1 + i2 + i3 == 3) | ((unsigned)(cs2 == 1) << 1)
                       | ((unsigned)(i2 && cs2 == total) << 2);
    const unsigned cb3 = (unsigned)(i2 + i3 + mr == 3) | ((unsigned)(cs3 == 1) << 1)
                       | ((unsigned)(i3 && cs3 == total) << 2);

    codes[(size_t)row * 256 + t] = cb0 | (cb1 << 8) | (cb2 << 16) | (cb3 << 24);
}

// ---------------- Kernel 2: streaming stencil, both channels/thread ----------------
__global__ __launch_bounds__(256) void stencil_kernel(
    const float* __restrict__ u, const unsigned int* __restrict__ codes,
    float* __restrict__ out)
{
    const int t  = blockIdx.x * 256 + threadIdx.x;   // row*256 + w4, row = b*1024+y
    const int w4 = t & 255;
    const int b  = t >> 18;                          // (t>>8) >> 10
    const int y  = (t >> 8) & 1023;

    const size_t u0 = (((size_t)(b * 2) << 10) + y) * WDIM + (w4 << 2);
    const size_t u1 = u0 + (size_t)WDIM * WDIM;

    // issue all loads up front
    const float4 v0 = *(const float4*)(u + u0);
    const float4 v1 = *(const float4*)(u + u1);
    float ul0 = 0.f, ur0 = 0.f, ul1 = 0.f, ur1 = 0.f;
    if (w4 != 0)   { ul0 = u[u0 - 1]; ul1 = u[u1 - 1]; }   // L1 hits
    if (w4 != 255) { ur0 = u[u0 + 4]; ur1 = u[u1 + 4]; }
    const unsigned cw = codes[t];

    // decode once, apply to both channels
    float fer[4], fe1[4], fe2[4];
    #pragma unroll
    for (int j = 0; j < 4; ++j) {
        const unsigned cb = (cw >> (8 * j)) & 7u;
        fer[j] = (float)(cb & 1u);
        fe1[j] = (float)((cb >> 1) & 1u);
        fe2[j] = (float)(cb >> 2);
    }

#define APPLY(V, UL, UR, DST)                                                   \
    {                                                                           \
        const float l0 = (UL), r0 = V.y;                                        \
        const float l1 = V.x,  r1 = V.z;                                        \
        const float l2 = V.y,  r2 = V.w;                                        \
        const float l3 = V.z,  r3 = (UR);                                       \
        v4f o;                                                                  \
        o.x = fer[0]*((r0-l0)*50.f) + fe1[0]*((r0-V.x)*100.f) + fe2[0]*((V.x-l0)*100.f); \
        o.y = fer[1]*((r1-l1)*50.f) + fe1[1]*((r1-V.y)*100.f) + fe2[1]*((V.y-l1)*100.f); \
        o.z = fer[2]*((r2-l2)*50.f) + fe1[2]*((r2-V.z)*100.f) + fe2[2]*((V.z-l2)*100.f); \
        o.w = fer[3]*((r3-l3)*50.f) + fe1[3]*((r3-V.w)*100.f) + fe2[3]*((V.w-l3)*100.f); \
        __builtin_nontemporal_store(o, (v4f*)(out + (DST)));                    \
    }
    APPLY(v0, ul0, ur0, u0)
    APPLY(v1, ul1, ur1, u1)
#undef APPLY
}

// ---------------- Fallback (ws too small): R4 fused kernel (verified) ----------------
__global__ __launch_bounds__(256, 4) void deriv_x_fused(
    const float* __restrict__ u, const float* __restrict__ mask,
    float* __restrict__ out)
{
    const int wave = threadIdx.x >> 6;
    const int lane = threadIdx.x & 63;
    const int row  = blockIdx.x * 4 + wave;
    const int b    = row >> 10;
    const int y    = row & 1023;

    const size_t mrow = (size_t)row * WDIM;
    const size_t u0r  = ((size_t)(b * 2) * WDIM + y) * WDIM;
    const size_t u1r  = u0r + (size_t)WDIM * WDIM;

    float4 a[4], d[4], mv[4];
    #pragma unroll
    for (int c = 0; c < 4; ++c) a[c] = *(const float4*)(u + u0r + c * 256 + lane * 4);
    #pragma unroll
    for (int c = 0; c < 4; ++c) d[c] = *(const float4*)(u + u1r + c * 256 + lane * 4);
    #pragma unroll
    for (int c = 0; c < 4; ++c) mv[c] = *(const float4*)(mask + mrow + c * 256 + lane * 4);

    ull b0[4], b1[4], b2[4], b3[4];
    #pragma unroll
    for (int c = 0; c < 4; ++c) {
        b0[c] = __ballot(mv[c].x != 0.0f);
        b1[c] = __ballot(mv[c].y != 0.0f);
        b2[c] = __ballot(mv[c].z != 0.0f);
        b3[c] = __ballot(mv[c].w != 0.0f);
    }
    int carry[4]; int runv = 0;
    #pragma unroll
    for (int c = 0; c < 4; ++c) {
        carry[c] = runv;
        runv += __popcll(b0[c]) + __popcll(b1[c]) + __popcll(b2[c]) + __popcll(b3[c]);
    }
    const int total = runv;
    const ull below = (1ull << lane) - 1ull;

    #pragma unroll
    for (int c = 0; c < 4; ++c) {
        const int i0 = (int)mv[c].x, i1 = (int)mv[c].y;
        const int i2 = (int)mv[c].z, i3 = (int)mv[c].w;
        const int pre = carry[c]
            + __popcll(b0[c] & below) + __popcll(b1[c] & below)
            + __popcll(b2[c] & below) + __popcll(b3[c] & below);
        const int cs0 = pre + i0, cs1 = cs0 + i1, cs2 = cs1 + i2, cs3 = cs2 + i3;
        const ull mlw = (b3[c] << 1) | (c > 0 ? (b3[c-1] >> 63) : 0ull);
        const ull mrw = (b0[c] >> 1) | (c < 3 ? (b0[c+1] << 63) : 0ull);
        const int ml = (int)((mlw >> lane) & 1ull);
        const int mr = (int)((mrw >> lane) & 1ull);
        const float er0 = (ml+i0+i1 == 3) ? 1.f : 0.f;
        const float er1 = (i0+i1+i2 == 3) ? 1.f : 0.f;
        const float er2 = (i1+i2+i3 == 3) ? 1.f : 0.f;
        const float er3 = (i2+i3+mr == 3) ? 1.f : 0.f;
        const float e10 = (cs0 == 1) ? 1.f : 0.f;
        const float e11 = (cs1 == 1) ? 1.f : 0.f;
        const float e12 = (cs2 == 1) ? 1.f : 0.f;
        const float e13 = (cs3 == 1) ? 1.f : 0.f;
        const float e20 = (i0 && cs0 == total) ? 1.f : 0.f;
        const float e21 = (i1 && cs1 == total) ? 1.f : 0.f;
        const float e22 = (i2 && cs2 == total) ? 1.f : 0.f;
        const float e23 = (i3 && cs3 == total) ? 1.f : 0.f;
        const int off = c * 256 + lane * 4;
#define DO_CH(ARR, ROFF)                                                            \
        {                                                                           \
            const float4 V = ARR[c];                                                \
            const float pubL = (lane == 63) ? (c > 0 ? ARR[c-1].w : 0.f) : V.w;     \
            const float pubR = (lane == 0)  ? (c < 3 ? ARR[c+1].x : 0.f) : V.x;     \
            const float ulx = __shfl(pubL, (lane + 63) & 63, 64);                   \
            const float urx = __shfl(pubR, (lane + 1) & 63, 64);                    \
            const float l0 = ulx, r0 = V.y;                                         \
            const float l1 = V.x, r1 = V.z;                                         \
            const float l2 = V.y, r2 = V.w;                                         \
            const float l3 = V.z, r3 = urx;                                         \
            v4f o;                                                                  \
            o.x = er0*((r0-l0)*50.f) + e10*((r0-V.x)*100.f) + e20*((V.x-l0)*100.f); \
            o.y = er1*((r1-l1)*50.f) + e11*((r1-V.y)*100.f) + e21*((V.y-l1)*100.f); \
            o.z = er2*((r2-l2)*50.f) + e12*((r2-V.z)*100.f) + e22*((V.z-l2)*100.f); \
            o.w = er3*((r3-l3)*50.f) + e13*((r3-V.w)*100.f) + e23*((V.w-l3)*100.f); \
            __builtin_nontemporal_store(o, (v4f*)(out + ROFF + off));               \
        }
        DO_CH(a, u0r)
        DO_CH(d, u1r)
#undef DO_CH
    }
}

extern "C" void kernel_launch(void* const* d_in, const int* in_sizes, int n_in,
                              void* d_out, int out_size, void* d_ws, size_t ws_size,
                              hipStream_t stream) {
    const float* u    = (const float*)d_in[0];
    const float* mask = (const float*)d_in[1];
    float* out        = (float*)d_out;

    const size_t codes_bytes = (size_t)16 * 1024 * 1024;  // 1 B/elem, [16,1024,1024]
    if (ws_size >= codes_bytes) {
        unsigned int* codes = (unsigned int*)d_ws;
        // K1: one block per row (16384), one float4 per thread
        mask_codes_kernel<<<dim3(16 * 1024), dim3(256), 0, stream>>>(mask, codes);
        // K2: one thread per (row, w4) = 16384*256 threads, both channels each
        stencil_kernel<<<dim3(16 * 1024), dim3(256), 0, stream>>>(u, codes, out);
    } else {
        deriv_x_fused<<<dim3(16 * 1024 / 4), dim3(256), 0, stream>>>(u, mask, out);
    }
}